// Round 5
// baseline (488.522 us; speedup 1.0000x reference)
//
#include <hip/hip_runtime.h>
#include <math.h>

#define MAXDEG 64

// -------------------- bf16 helpers --------------------
static __device__ inline float bf2f(unsigned short u) {
    return __uint_as_float(((unsigned int)u) << 16);
}
static __device__ inline unsigned short f2bf(float f) {
    unsigned int u = __float_as_uint(f);
    u += 0x7FFFu + ((u >> 16) & 1u);  // round-nearest-even
    return (unsigned short)(u >> 16);
}
static __device__ inline float4 ld_f4(const float* p) { return *(const float4*)p; }

// -------------------- GEMM phases --------------------
// 256-thread: sA (64x128 fp32 LDS) @ W (128x128) -> Y bf16
static __device__ __forceinline__ void gemm128_phase256(
    const float* sA, const float* __restrict__ W,
    unsigned short* __restrict__ Y, int row0, int t, int N) {
    int tx = t & 31, ty = t >> 5;
    int c0 = tx * 4, r0 = ty * 8;
    float acc[8][4];
#pragma unroll
    for (int i = 0; i < 8; ++i)
#pragma unroll
        for (int c = 0; c < 4; ++c) acc[i][c] = 0.f;

    for (int j = 0; j < 128; j += 4) {
        float w[4][4];
#pragma unroll
        for (int q = 0; q < 4; ++q) {
            float4 t4 = ld_f4(&W[(size_t)(j + q) * 128 + c0]);
            w[q][0] = t4.x; w[q][1] = t4.y; w[q][2] = t4.z; w[q][3] = t4.w;
        }
#pragma unroll
        for (int i = 0; i < 8; ++i) {
            float4 a4 = ld_f4(&sA[(r0 + i) * 128 + j]);
            float a[4] = {a4.x, a4.y, a4.z, a4.w};
#pragma unroll
            for (int q = 0; q < 4; ++q)
#pragma unroll
                for (int c = 0; c < 4; ++c)
                    acc[i][c] = fmaf(a[q], w[q][c], acc[i][c]);
        }
    }
#pragma unroll
    for (int i = 0; i < 8; ++i) {
        int grow = row0 + r0 + i;
        if (grow < N) {
            ushort4 o;
            o.x = f2bf(acc[i][0]); o.y = f2bf(acc[i][1]);
            o.z = f2bf(acc[i][2]); o.w = f2bf(acc[i][3]);
            *(ushort4*)&Y[(size_t)grow * 128 + c0] = o;
        }
    }
}

// 512-thread: sA @ W (128x128) -> Y bf16 (4 rows x 4 cols / thread)
static __device__ __forceinline__ void gemm128_phase512(
    const float* sA, const float* __restrict__ W,
    unsigned short* __restrict__ Y, int row0, int t, int N) {
    int tx = t & 31, ty = t >> 5;   // ty 0..15
    int c0 = tx * 4, r0 = ty * 4;
    float acc[4][4];
#pragma unroll
    for (int i = 0; i < 4; ++i)
#pragma unroll
        for (int c = 0; c < 4; ++c) acc[i][c] = 0.f;

    for (int j = 0; j < 128; j += 4) {
        float w[4][4];
#pragma unroll
        for (int q = 0; q < 4; ++q) {
            float4 t4 = ld_f4(&W[(size_t)(j + q) * 128 + c0]);
            w[q][0] = t4.x; w[q][1] = t4.y; w[q][2] = t4.z; w[q][3] = t4.w;
        }
#pragma unroll
        for (int i = 0; i < 4; ++i) {
            float4 a4 = ld_f4(&sA[(r0 + i) * 128 + j]);
            float a[4] = {a4.x, a4.y, a4.z, a4.w};
#pragma unroll
            for (int q = 0; q < 4; ++q)
#pragma unroll
                for (int c = 0; c < 4; ++c)
                    acc[i][c] = fmaf(a[q], w[q][c], acc[i][c]);
        }
    }
#pragma unroll
    for (int i = 0; i < 4; ++i) {
        int grow = row0 + r0 + i;
        if (grow < N) {
            ushort4 o;
            o.x = f2bf(acc[i][0]); o.y = f2bf(acc[i][1]);
            o.z = f2bf(acc[i][2]); o.w = f2bf(acc[i][3]);
            *(ushort4*)&Y[(size_t)grow * 128 + c0] = o;
        }
    }
}

// 512-thread: sA @ W2 (128x40) -> Y3 bf16 (2 rows x 4 cols / thread, tx<10)
static __device__ __forceinline__ void gemm40_phase512(
    const float* sA, const float* __restrict__ W2,
    unsigned short* __restrict__ Y3, int row0, int t, int N) {
    int tx = t & 15, ty = t >> 4;   // ty 0..31
    int c0 = tx * 4, r0 = ty * 2;
    if (tx >= 10) return;
    float acc[2][4];
#pragma unroll
    for (int i = 0; i < 2; ++i)
#pragma unroll
        for (int c = 0; c < 4; ++c) acc[i][c] = 0.f;

    for (int j = 0; j < 128; j += 4) {
        float w[4][4];
#pragma unroll
        for (int q = 0; q < 4; ++q) {
            float4 t4 = ld_f4(&W2[(size_t)(j + q) * 40 + c0]);
            w[q][0] = t4.x; w[q][1] = t4.y; w[q][2] = t4.z; w[q][3] = t4.w;
        }
#pragma unroll
        for (int i = 0; i < 2; ++i) {
            float4 a4 = ld_f4(&sA[(r0 + i) * 128 + j]);
            float a[4] = {a4.x, a4.y, a4.z, a4.w};
#pragma unroll
            for (int q = 0; q < 4; ++q)
#pragma unroll
                for (int c = 0; c < 4; ++c)
                    acc[i][c] = fmaf(a[q], w[q][c], acc[i][c]);
        }
    }
#pragma unroll
    for (int i = 0; i < 2; ++i) {
        int grow = row0 + r0 + i;
        if (grow < N) {
            ushort4 o;
            o.x = f2bf(acc[i][0]); o.y = f2bf(acc[i][1]);
            o.z = f2bf(acc[i][2]); o.w = f2bf(acc[i][3]);
            *(ushort4*)&Y3[(size_t)grow * 40 + c0] = o;
        }
    }
}

// -------------------- gather phase (512 threads, 2 rows/wave) --------------------
// MODE 0 (layer2 in): a = relu(agg) * ln[node]
// MODE 1 (layer3 in): a = relu(agg * rn[node]) * ln[node]
template <int MODE>
static __device__ __forceinline__ void gather_phase(
    const unsigned short* __restrict__ Ysrc, float* sA,
    const int* __restrict__ csr, const int* __restrict__ indeg,
    const int* __restrict__ outdeg, int row0, int t, int N) {
    int wv = t >> 6;            // wave 0..7
    int lane = t & 63;
    int half = (t >> 5) & 1;    // half-wave: which row of the pair
    int lx = t & 31;            // lane within half
    int hbase = half * 32;

#pragma unroll
    for (int i = 0; i < 4; ++i) {
        int r = (i * 8 + wv) * 2 + half;   // 0..63
        int node = row0 + r;
        bool valid = node < N;
        int d = 0, dc = 0;
        if (valid) {
            d = indeg[node];
            dc = d > MAXDEG ? MAXDEG : d;
        }
        // stage this row's src indices across my half-wave (2 regs cover 64)
        int idx0 = 0, idx1 = 0;
        if (valid && lx < dc) idx0 = csr[node * MAXDEG + lx];
        if (valid && lx + 32 < dc) idx1 = csr[node * MAXDEG + 32 + lx];
        // wave-uniform pair max degree
        int dother = __shfl(dc, lane ^ 32);
        int dmax = dc > dother ? dc : dother;

        float a0 = 0.f, a1 = 0.f, a2 = 0.f, a3 = 0.f;
        for (int e = 0; e < dmax; e += 4) {
            bool lo = e < 32;                       // uniform (e % 4 == 0)
            int v = lo ? idx0 : idx1;
            int base = hbase + (lo ? e : e - 32);
            int s0 = __shfl(v, base);
            int s1 = __shfl(v, base + 1);
            int s2 = __shfl(v, base + 2);
            int s3 = __shfl(v, base + 3);
            if (e + 0 < dc) {
                ushort4 u = *(const ushort4*)&Ysrc[(size_t)s0 * 128 + lx * 4];
                a0 += bf2f(u.x); a1 += bf2f(u.y); a2 += bf2f(u.z); a3 += bf2f(u.w);
            }
            if (e + 1 < dc) {
                ushort4 u = *(const ushort4*)&Ysrc[(size_t)s1 * 128 + lx * 4];
                a0 += bf2f(u.x); a1 += bf2f(u.y); a2 += bf2f(u.z); a3 += bf2f(u.w);
            }
            if (e + 2 < dc) {
                ushort4 u = *(const ushort4*)&Ysrc[(size_t)s2 * 128 + lx * 4];
                a0 += bf2f(u.x); a1 += bf2f(u.y); a2 += bf2f(u.z); a3 += bf2f(u.w);
            }
            if (e + 3 < dc) {
                ushort4 u = *(const ushort4*)&Ysrc[(size_t)s3 * 128 + lx * 4];
                a0 += bf2f(u.x); a1 += bf2f(u.y); a2 += bf2f(u.z); a3 += bf2f(u.w);
            }
        }
        if (valid) {
            int od = outdeg[node];
            float ln = rsqrtf((float)(od > 1 ? od : 1));
            if (MODE == 0) {
                a0 = fmaxf(a0, 0.f) * ln;
                a1 = fmaxf(a1, 0.f) * ln;
                a2 = fmaxf(a2, 0.f) * ln;
                a3 = fmaxf(a3, 0.f) * ln;
            } else {
                float rn = rsqrtf((float)(d > 1 ? d : 1));
                a0 = fmaxf(a0 * rn, 0.f) * ln;
                a1 = fmaxf(a1 * rn, 0.f) * ln;
                a2 = fmaxf(a2 * rn, 0.f) * ln;
                a3 = fmaxf(a3 * rn, 0.f) * ln;
            }
        }
        *(float4*)&sA[r * 128 + lx * 4] = make_float4(a0, a1, a2, a3);
    }
}

// ==================== K1: CSR build + outdeg hist || GEMM1 ====================
static __global__ __launch_bounds__(256) void edge_gemm1_kernel(
    const float* __restrict__ A, const float* __restrict__ W,
    unsigned short* __restrict__ Y,
    const int* __restrict__ src, const int* __restrict__ dst,
    int* __restrict__ outdeg, int* __restrict__ indeg, int* __restrict__ csr,
    int N, int E, int gG, int gE) {
    __shared__ float sA[64 * 128];
    int bid = blockIdx.x;
    int t = threadIdx.x;

    int m = gG < gE ? gG : gE;
    int role, idx;
    if (bid < 2 * m) { role = bid & 1; idx = bid >> 1; }
    else { idx = m + (bid - 2 * m); role = (gG > gE) ? 0 : 1; }

    if (role == 1) {
        int base = idx * 2048 + t * 8;
        if (base + 8 <= E) {
            int4 s0 = *(const int4*)&src[base];
            int4 s1 = *(const int4*)&src[base + 4];
            int4 d0 = *(const int4*)&dst[base];
            int4 d1 = *(const int4*)&dst[base + 4];
            int p0 = atomicAdd(&indeg[d0.x], 1);
            int p1 = atomicAdd(&indeg[d0.y], 1);
            int p2 = atomicAdd(&indeg[d0.z], 1);
            int p3 = atomicAdd(&indeg[d0.w], 1);
            int p4 = atomicAdd(&indeg[d1.x], 1);
            int p5 = atomicAdd(&indeg[d1.y], 1);
            int p6 = atomicAdd(&indeg[d1.z], 1);
            int p7 = atomicAdd(&indeg[d1.w], 1);
            atomicAdd(&outdeg[s0.x], 1); atomicAdd(&outdeg[s0.y], 1);
            atomicAdd(&outdeg[s0.z], 1); atomicAdd(&outdeg[s0.w], 1);
            atomicAdd(&outdeg[s1.x], 1); atomicAdd(&outdeg[s1.y], 1);
            atomicAdd(&outdeg[s1.z], 1); atomicAdd(&outdeg[s1.w], 1);
            if (p0 < MAXDEG) csr[d0.x * MAXDEG + p0] = s0.x;
            if (p1 < MAXDEG) csr[d0.y * MAXDEG + p1] = s0.y;
            if (p2 < MAXDEG) csr[d0.z * MAXDEG + p2] = s0.z;
            if (p3 < MAXDEG) csr[d0.w * MAXDEG + p3] = s0.w;
            if (p4 < MAXDEG) csr[d1.x * MAXDEG + p4] = s1.x;
            if (p5 < MAXDEG) csr[d1.y * MAXDEG + p5] = s1.y;
            if (p6 < MAXDEG) csr[d1.z * MAXDEG + p6] = s1.z;
            if (p7 < MAXDEG) csr[d1.w * MAXDEG + p7] = s1.w;
        } else {
            for (int e = base; e < E; ++e) {
                int s = src[e], d = dst[e];
                atomicAdd(&outdeg[s], 1);
                int p = atomicAdd(&indeg[d], 1);
                if (p < MAXDEG) csr[d * MAXDEG + p] = s;
            }
        }
        return;
    }

    // ---- gemm1 ----
    int row0 = idx * 64;
#pragma unroll
    for (int i = 0; i < 8; ++i) {
        int fi = i * 256 + t;
        int r = fi >> 5;
        int c4 = (fi & 31) * 4;
        int grow = row0 + r;
        float4 v = make_float4(0.f, 0.f, 0.f, 0.f);
        if (grow < N) v = ld_f4(&A[(size_t)grow * 128 + c4]);
        *(float4*)&sA[r * 128 + c4] = v;
    }
    __syncthreads();
    gemm128_phase256(sA, W, Y, row0, t, N);
}

// ==================== K2: agg(Y1)+relu+ln @ Wh ====================
static __global__ __launch_bounds__(512) void agg_gemm2_kernel(
    const unsigned short* __restrict__ Y1, const float* __restrict__ Wh,
    unsigned short* __restrict__ Y2,
    const int* __restrict__ csr, const int* __restrict__ indeg,
    const int* __restrict__ outdeg, int N) {
    __shared__ float sA[64 * 128];
    int t = threadIdx.x;
    int row0 = blockIdx.x * 64;
    gather_phase<0>(Y1, sA, csr, indeg, outdeg, row0, t, N);
    __syncthreads();
    gemm128_phase512(sA, Wh, Y2, row0, t, N);
}

// ==================== K3: agg(Y2)*rn,relu,*ln @ W2 ====================
static __global__ __launch_bounds__(512) void agg_gemm3_kernel(
    const unsigned short* __restrict__ Y2, const float* __restrict__ W2,
    unsigned short* __restrict__ Y3,
    const int* __restrict__ csr, const int* __restrict__ indeg,
    const int* __restrict__ outdeg, int N) {
    __shared__ float sA[64 * 128];
    int t = threadIdx.x;
    int row0 = blockIdx.x * 64;
    gather_phase<1>(Y2, sA, csr, indeg, outdeg, row0, t, N);
    __syncthreads();
    gemm40_phase512(sA, W2, Y3, row0, t, N);
}

// ========== K4: agg(Y3)*rn + b2 + log_softmax ==========
static __global__ __launch_bounds__(512) void agg40_lsm_kernel(
    const unsigned short* __restrict__ Y3, const float* __restrict__ b2,
    const int* __restrict__ csr, const int* __restrict__ indeg,
    float* __restrict__ out, int N) {
    int t = threadIdx.x;
    int node = blockIdx.x * 8 + (t >> 6);
    if (node >= N) return;
    int lane = t & 63;
    int grp = lane >> 4;   // 0..3  : edge group
    int sub = lane & 15;   // 0..15 : dim group (10 active)
    int d = indeg[node];
    int dc = d > MAXDEG ? MAXDEG : d;

    float a0 = 0.f, a1 = 0.f, a2 = 0.f, a3 = 0.f;
    if (sub < 10) {
        int e = grp;
        for (; e + 4 < dc; e += 8) {
            int s0 = csr[node * MAXDEG + e];
            int s1 = csr[node * MAXDEG + e + 4];
            ushort4 u0 = *(const ushort4*)&Y3[(size_t)s0 * 40 + sub * 4];
            ushort4 u1 = *(const ushort4*)&Y3[(size_t)s1 * 40 + sub * 4];
            a0 += bf2f(u0.x) + bf2f(u1.x);
            a1 += bf2f(u0.y) + bf2f(u1.y);
            a2 += bf2f(u0.z) + bf2f(u1.z);
            a3 += bf2f(u0.w) + bf2f(u1.w);
        }
        if (e < dc) {
            int s = csr[node * MAXDEG + e];
            ushort4 u = *(const ushort4*)&Y3[(size_t)s * 40 + sub * 4];
            a0 += bf2f(u.x); a1 += bf2f(u.y); a2 += bf2f(u.z); a3 += bf2f(u.w);
        }
    }
    a0 += __shfl_xor(a0, 16); a0 += __shfl_xor(a0, 32);
    a1 += __shfl_xor(a1, 16); a1 += __shfl_xor(a1, 32);
    a2 += __shfl_xor(a2, 16); a2 += __shfl_xor(a2, 32);
    a3 += __shfl_xor(a3, 16); a3 += __shfl_xor(a3, 32);

    float rs = rsqrtf((float)(d > 1 ? d : 1));
    float x0 = 0.f, x1 = 0.f, x2 = 0.f, x3 = 0.f;
    float mx = -INFINITY;
    if (sub < 10) {
        float4 b = *(const float4*)&b2[sub * 4];
        x0 = a0 * rs + b.x;
        x1 = a1 * rs + b.y;
        x2 = a2 * rs + b.z;
        x3 = a3 * rs + b.w;
        mx = fmaxf(fmaxf(x0, x1), fmaxf(x2, x3));
    }
#pragma unroll
    for (int o = 1; o < 16; o <<= 1) mx = fmaxf(mx, __shfl_xor(mx, o));
    float ex = 0.f;
    if (sub < 10)
        ex = expf(x0 - mx) + expf(x1 - mx) + expf(x2 - mx) + expf(x3 - mx);
#pragma unroll
    for (int o = 1; o < 16; o <<= 1) ex += __shfl_xor(ex, o);
    float ls = logf(ex) + mx;
    if (sub < 10 && grp == 0)
        *(float4*)&out[(size_t)node * 40 + sub * 4] =
            make_float4(x0 - ls, x1 - ls, x2 - ls, x3 - ls);
}

// -------------------- launch --------------------

extern "C" void kernel_launch(void* const* d_in, const int* in_sizes, int n_in,
                              void* d_out, int out_size, void* d_ws, size_t ws_size,
                              hipStream_t stream) {
    const float* features = (const float*)d_in[0];
    const int* src = (const int*)d_in[1];
    const int* dst = (const int*)d_in[2];
    const float* W1 = (const float*)d_in[3];
    const float* Wh = (const float*)d_in[4];
    const float* W2 = (const float*)d_in[5];
    const float* b2 = (const float*)d_in[6];
    float* out = (float*)d_out;

    const int N = in_sizes[0] / 128;
    const int E = in_sizes[1];

    char* p = (char*)d_ws;
    auto carve = [&](size_t bytes) {
        char* q = p;
        p += (bytes + 255) & ~(size_t)255;
        return q;
    };
    unsigned short* bufY1 = (unsigned short*)carve((size_t)N * 128 * 2);
    unsigned short* bufY2 = (unsigned short*)carve((size_t)N * 128 * 2);
    unsigned short* bufY3 = (unsigned short*)carve((size_t)N * 40 * 2);
    int* csr = (int*)carve((size_t)N * MAXDEG * 4);
    int* outdeg = (int*)carve((size_t)N * 4);
    int* indeg = (int*)carve((size_t)N * 4);
    (void)ws_size; (void)n_in; (void)out_size;

    hipMemsetAsync(outdeg, 0, (size_t)N * 4, stream);
    hipMemsetAsync(indeg, 0, (size_t)N * 4, stream);

    int gG = (N + 63) / 64;          // gemm blocks (1563)
    int gE = (E + 2047) / 2048;      // edge blocks, 8 edges/thread (782)
    // K1: CSR build + outdeg hist || gemm1
    edge_gemm1_kernel<<<gG + gE, 256, 0, stream>>>(
        features, W1, bufY1, src, dst, outdeg, indeg, csr, N, E, gG, gE);
    // K2: Y2 = (relu(agg(Y1)) * ln) @ Wh
    agg_gemm2_kernel<<<gG, 512, 0, stream>>>(bufY1, Wh, bufY2, csr, indeg, outdeg, N);
    // K3: Y3 = (relu(agg(Y2) * rn) * ln) @ W2
    agg_gemm3_kernel<<<gG, 512, 0, stream>>>(bufY2, W2, bufY3, csr, indeg, outdeg, N);
    // K4: out = log_softmax(agg(Y3) * rn + b2)
    agg40_lsm_kernel<<<(N + 7) / 8, 512, 0, stream>>>(bufY3, b2, csr, indeg, out, N);
}

// Round 6
// 420.035 us; speedup vs baseline: 1.1631x; 1.1631x over previous
//
#include <hip/hip_runtime.h>
#include <math.h>

#define MAXDEG 64

// -------------------- bf16 helpers --------------------
static __device__ inline unsigned short f2bf(float f) {
    unsigned int u = __float_as_uint(f);
    u += 0x7FFFu + ((u >> 16) & 1u);  // round-nearest-even
    return (unsigned short)(u >> 16);
}
static __device__ inline float bf2f(unsigned short u) {
    return __uint_as_float(((unsigned int)u) << 16);
}
static __device__ inline float4 ld_f4(const float* p) { return *(const float4*)p; }

// accumulate 8 bf16 (packed in uint4) into 8 f32
static __device__ __forceinline__ void acc8(float* a, uint4 u) {
    a[0] += __uint_as_float(u.x << 16);
    a[1] += __uint_as_float(u.x & 0xFFFF0000u);
    a[2] += __uint_as_float(u.y << 16);
    a[3] += __uint_as_float(u.y & 0xFFFF0000u);
    a[4] += __uint_as_float(u.z << 16);
    a[5] += __uint_as_float(u.z & 0xFFFF0000u);
    a[6] += __uint_as_float(u.w << 16);
    a[7] += __uint_as_float(u.w & 0xFFFF0000u);
}

// -------------------- GEMM phases --------------------
// 256-thread: sA (64x128 fp32 LDS) @ W (128x128) -> Y bf16
static __device__ __forceinline__ void gemm128_phase256(
    const float* sA, const float* __restrict__ W,
    unsigned short* __restrict__ Y, int row0, int t, int N) {
    int tx = t & 31, ty = t >> 5;
    int c0 = tx * 4, r0 = ty * 8;
    float acc[8][4];
#pragma unroll
    for (int i = 0; i < 8; ++i)
#pragma unroll
        for (int c = 0; c < 4; ++c) acc[i][c] = 0.f;

    for (int j = 0; j < 128; j += 4) {
        float w[4][4];
#pragma unroll
        for (int q = 0; q < 4; ++q) {
            float4 t4 = ld_f4(&W[(size_t)(j + q) * 128 + c0]);
            w[q][0] = t4.x; w[q][1] = t4.y; w[q][2] = t4.z; w[q][3] = t4.w;
        }
#pragma unroll
        for (int i = 0; i < 8; ++i) {
            float4 a4 = ld_f4(&sA[(r0 + i) * 128 + j]);
            float a[4] = {a4.x, a4.y, a4.z, a4.w};
#pragma unroll
            for (int q = 0; q < 4; ++q)
#pragma unroll
                for (int c = 0; c < 4; ++c)
                    acc[i][c] = fmaf(a[q], w[q][c], acc[i][c]);
        }
    }
#pragma unroll
    for (int i = 0; i < 8; ++i) {
        int grow = row0 + r0 + i;
        if (grow < N) {
            ushort4 o;
            o.x = f2bf(acc[i][0]); o.y = f2bf(acc[i][1]);
            o.z = f2bf(acc[i][2]); o.w = f2bf(acc[i][3]);
            *(ushort4*)&Y[(size_t)grow * 128 + c0] = o;
        }
    }
}

// 512-thread: sA @ W (128x128) -> Y bf16 (4 rows x 4 cols / thread)
static __device__ __forceinline__ void gemm128_phase512(
    const float* sA, const float* __restrict__ W,
    unsigned short* __restrict__ Y, int row0, int t, int N) {
    int tx = t & 31, ty = t >> 5;   // ty 0..15
    int c0 = tx * 4, r0 = ty * 4;
    float acc[4][4];
#pragma unroll
    for (int i = 0; i < 4; ++i)
#pragma unroll
        for (int c = 0; c < 4; ++c) acc[i][c] = 0.f;

    for (int j = 0; j < 128; j += 4) {
        float w[4][4];
#pragma unroll
        for (int q = 0; q < 4; ++q) {
            float4 t4 = ld_f4(&W[(size_t)(j + q) * 128 + c0]);
            w[q][0] = t4.x; w[q][1] = t4.y; w[q][2] = t4.z; w[q][3] = t4.w;
        }
#pragma unroll
        for (int i = 0; i < 4; ++i) {
            float4 a4 = ld_f4(&sA[(r0 + i) * 128 + j]);
            float a[4] = {a4.x, a4.y, a4.z, a4.w};
#pragma unroll
            for (int q = 0; q < 4; ++q)
#pragma unroll
                for (int c = 0; c < 4; ++c)
                    acc[i][c] = fmaf(a[q], w[q][c], acc[i][c]);
        }
    }
#pragma unroll
    for (int i = 0; i < 4; ++i) {
        int grow = row0 + r0 + i;
        if (grow < N) {
            ushort4 o;
            o.x = f2bf(acc[i][0]); o.y = f2bf(acc[i][1]);
            o.z = f2bf(acc[i][2]); o.w = f2bf(acc[i][3]);
            *(ushort4*)&Y[(size_t)grow * 128 + c0] = o;
        }
    }
}

// 512-thread: sA @ W2 (128x40) -> Y3 bf16 (2 rows x 4 cols / thread, tx<10)
static __device__ __forceinline__ void gemm40_phase512(
    const float* sA, const float* __restrict__ W2,
    unsigned short* __restrict__ Y3, int row0, int t, int N) {
    int tx = t & 15, ty = t >> 4;   // ty 0..31
    int c0 = tx * 4, r0 = ty * 2;
    if (tx >= 10) return;
    float acc[2][4];
#pragma unroll
    for (int i = 0; i < 2; ++i)
#pragma unroll
        for (int c = 0; c < 4; ++c) acc[i][c] = 0.f;

    for (int j = 0; j < 128; j += 4) {
        float w[4][4];
#pragma unroll
        for (int q = 0; q < 4; ++q) {
            float4 t4 = ld_f4(&W2[(size_t)(j + q) * 40 + c0]);
            w[q][0] = t4.x; w[q][1] = t4.y; w[q][2] = t4.z; w[q][3] = t4.w;
        }
#pragma unroll
        for (int i = 0; i < 2; ++i) {
            float4 a4 = ld_f4(&sA[(r0 + i) * 128 + j]);
            float a[4] = {a4.x, a4.y, a4.z, a4.w};
#pragma unroll
            for (int q = 0; q < 4; ++q)
#pragma unroll
                for (int c = 0; c < 4; ++c)
                    acc[i][c] = fmaf(a[q], w[q][c], acc[i][c]);
        }
    }
#pragma unroll
    for (int i = 0; i < 2; ++i) {
        int grow = row0 + r0 + i;
        if (grow < N) {
            ushort4 o;
            o.x = f2bf(acc[i][0]); o.y = f2bf(acc[i][1]);
            o.z = f2bf(acc[i][2]); o.w = f2bf(acc[i][3]);
            *(ushort4*)&Y3[(size_t)grow * 40 + c0] = o;
        }
    }
}

// -------------------- gather phase (512 threads) --------------------
// 16 lanes per row (ushort8 = 16B/lane), 4 rows per wave, 4-edge unroll.
// All shuffle sources live in the same 16-lane quarter (same control flow).
// MODE 0 (layer2 in): a = relu(agg) * ln[node]
// MODE 1 (layer3 in): a = relu(agg * rn[node]) * ln[node]
template <int MODE>
static __device__ __forceinline__ void gather_phase(
    const unsigned short* __restrict__ Ysrc, float* sA,
    const int* __restrict__ csr, const int* __restrict__ indeg,
    const int* __restrict__ outdeg, int row0, int t, int N) {
    int w = t >> 6;             // wave 0..7
    int l = t & 63;
    int q = l >> 4;             // quarter 0..3 (one row each)
    int lq = l & 15;            // lane within quarter
    int qb = q * 16;            // quarter's base lane in wave

#pragma unroll
    for (int i = 0; i < 2; ++i) {
        int r = i * 32 + w * 4 + q;   // 0..63
        int node = row0 + r;
        bool valid = node < N;
        int d = 0;
        if (valid) d = indeg[node];
        int dc = d > MAXDEG ? MAXDEG : d;

        // stage up to 64 src indices in 4 regs across the 16-lane quarter
        int idx0 = 0, idx1 = 0, idx2 = 0, idx3 = 0;
        if (valid) {
            const int* cp = csr + (size_t)node * MAXDEG;
            idx0 = cp[lq];
            idx1 = cp[16 + lq];
            idx2 = cp[32 + lq];
            idx3 = cp[48 + lq];
        }

        float a[8];
#pragma unroll
        for (int x = 0; x < 8; ++x) a[x] = 0.f;

#pragma unroll
        for (int k = 0; k < 4; ++k) {
            int kbase = k * 16;
            if (kbase >= dc) break;
            int v = (k == 0) ? idx0 : (k == 1) ? idx1 : (k == 2) ? idx2 : idx3;
            int lim = dc - kbase;
            if (lim > 16) lim = 16;
            int e = 0;
            for (; e + 4 <= lim; e += 4) {
                int s0 = __shfl(v, qb + e);
                int s1 = __shfl(v, qb + e + 1);
                int s2 = __shfl(v, qb + e + 2);
                int s3 = __shfl(v, qb + e + 3);
                uint4 u0 = *(const uint4*)&Ysrc[(size_t)s0 * 128 + lq * 8];
                uint4 u1 = *(const uint4*)&Ysrc[(size_t)s1 * 128 + lq * 8];
                uint4 u2 = *(const uint4*)&Ysrc[(size_t)s2 * 128 + lq * 8];
                uint4 u3 = *(const uint4*)&Ysrc[(size_t)s3 * 128 + lq * 8];
                acc8(a, u0); acc8(a, u1); acc8(a, u2); acc8(a, u3);
            }
            for (; e < lim; ++e) {
                int s0 = __shfl(v, qb + e);
                uint4 u0 = *(const uint4*)&Ysrc[(size_t)s0 * 128 + lq * 8];
                acc8(a, u0);
            }
        }

        if (valid) {
            int od = outdeg[node];
            float ln = rsqrtf((float)(od > 1 ? od : 1));
            if (MODE == 0) {
#pragma unroll
                for (int x = 0; x < 8; ++x) a[x] = fmaxf(a[x], 0.f) * ln;
            } else {
                float rn = rsqrtf((float)(d > 1 ? d : 1));
#pragma unroll
                for (int x = 0; x < 8; ++x) a[x] = fmaxf(a[x] * rn, 0.f) * ln;
            }
        }
        *(float4*)&sA[r * 128 + lq * 8] = make_float4(a[0], a[1], a[2], a[3]);
        *(float4*)&sA[r * 128 + lq * 8 + 4] = make_float4(a[4], a[5], a[6], a[7]);
    }
}

// ==================== K1: CSR build + outdeg hist || GEMM1 ====================
static __global__ __launch_bounds__(256) void edge_gemm1_kernel(
    const float* __restrict__ A, const float* __restrict__ W,
    unsigned short* __restrict__ Y,
    const int* __restrict__ src, const int* __restrict__ dst,
    int* __restrict__ outdeg, int* __restrict__ indeg, int* __restrict__ csr,
    int N, int E, int gG, int gE) {
    __shared__ float sA[64 * 128];
    int bid = blockIdx.x;
    int t = threadIdx.x;

    int m = gG < gE ? gG : gE;
    int role, idx;
    if (bid < 2 * m) { role = bid & 1; idx = bid >> 1; }
    else { idx = m + (bid - 2 * m); role = (gG > gE) ? 0 : 1; }

    if (role == 1) {
        int base = idx * 2048 + t * 8;
        if (base + 8 <= E) {
            int4 s0 = *(const int4*)&src[base];
            int4 s1 = *(const int4*)&src[base + 4];
            int4 d0 = *(const int4*)&dst[base];
            int4 d1 = *(const int4*)&dst[base + 4];
            int p0 = atomicAdd(&indeg[d0.x], 1);
            int p1 = atomicAdd(&indeg[d0.y], 1);
            int p2 = atomicAdd(&indeg[d0.z], 1);
            int p3 = atomicAdd(&indeg[d0.w], 1);
            int p4 = atomicAdd(&indeg[d1.x], 1);
            int p5 = atomicAdd(&indeg[d1.y], 1);
            int p6 = atomicAdd(&indeg[d1.z], 1);
            int p7 = atomicAdd(&indeg[d1.w], 1);
            atomicAdd(&outdeg[s0.x], 1); atomicAdd(&outdeg[s0.y], 1);
            atomicAdd(&outdeg[s0.z], 1); atomicAdd(&outdeg[s0.w], 1);
            atomicAdd(&outdeg[s1.x], 1); atomicAdd(&outdeg[s1.y], 1);
            atomicAdd(&outdeg[s1.z], 1); atomicAdd(&outdeg[s1.w], 1);
            if (p0 < MAXDEG) csr[d0.x * MAXDEG + p0] = s0.x;
            if (p1 < MAXDEG) csr[d0.y * MAXDEG + p1] = s0.y;
            if (p2 < MAXDEG) csr[d0.z * MAXDEG + p2] = s0.z;
            if (p3 < MAXDEG) csr[d0.w * MAXDEG + p3] = s0.w;
            if (p4 < MAXDEG) csr[d1.x * MAXDEG + p4] = s1.x;
            if (p5 < MAXDEG) csr[d1.y * MAXDEG + p5] = s1.y;
            if (p6 < MAXDEG) csr[d1.z * MAXDEG + p6] = s1.z;
            if (p7 < MAXDEG) csr[d1.w * MAXDEG + p7] = s1.w;
        } else {
            for (int e = base; e < E; ++e) {
                int s = src[e], d = dst[e];
                atomicAdd(&outdeg[s], 1);
                int p = atomicAdd(&indeg[d], 1);
                if (p < MAXDEG) csr[d * MAXDEG + p] = s;
            }
        }
        return;
    }

    // ---- gemm1 ----
    int row0 = idx * 64;
#pragma unroll
    for (int i = 0; i < 8; ++i) {
        int fi = i * 256 + t;
        int r = fi >> 5;
        int c4 = (fi & 31) * 4;
        int grow = row0 + r;
        float4 v = make_float4(0.f, 0.f, 0.f, 0.f);
        if (grow < N) v = ld_f4(&A[(size_t)grow * 128 + c4]);
        *(float4*)&sA[r * 128 + c4] = v;
    }
    __syncthreads();
    gemm128_phase256(sA, W, Y, row0, t, N);
}

// ==================== K2: agg(Y1)+relu+ln @ Wh ====================
static __global__ __launch_bounds__(512) void agg_gemm2_kernel(
    const unsigned short* __restrict__ Y1, const float* __restrict__ Wh,
    unsigned short* __restrict__ Y2,
    const int* __restrict__ csr, const int* __restrict__ indeg,
    const int* __restrict__ outdeg, int N) {
    __shared__ float sA[64 * 128];
    int t = threadIdx.x;
    int row0 = blockIdx.x * 64;
    gather_phase<0>(Y1, sA, csr, indeg, outdeg, row0, t, N);
    __syncthreads();
    gemm128_phase512(sA, Wh, Y2, row0, t, N);
}

// ==================== K3: agg(Y2)*rn,relu,*ln @ W2 ====================
static __global__ __launch_bounds__(512) void agg_gemm3_kernel(
    const unsigned short* __restrict__ Y2, const float* __restrict__ W2,
    unsigned short* __restrict__ Y3,
    const int* __restrict__ csr, const int* __restrict__ indeg,
    const int* __restrict__ outdeg, int N) {
    __shared__ float sA[64 * 128];
    int t = threadIdx.x;
    int row0 = blockIdx.x * 64;
    gather_phase<1>(Y2, sA, csr, indeg, outdeg, row0, t, N);
    __syncthreads();
    gemm40_phase512(sA, W2, Y3, row0, t, N);
}

// ========== K4: agg(Y3)*rn + b2 + log_softmax ==========
static __global__ __launch_bounds__(512) void agg40_lsm_kernel(
    const unsigned short* __restrict__ Y3, const float* __restrict__ b2,
    const int* __restrict__ csr, const int* __restrict__ indeg,
    float* __restrict__ out, int N) {
    int t = threadIdx.x;
    int node = blockIdx.x * 8 + (t >> 6);
    if (node >= N) return;
    int lane = t & 63;
    int grp = lane >> 4;   // 0..3  : edge group
    int sub = lane & 15;   // 0..15 : dim group (10 active)
    int d = indeg[node];
    int dc = d > MAXDEG ? MAXDEG : d;

    float a0 = 0.f, a1 = 0.f, a2 = 0.f, a3 = 0.f;
    if (sub < 10) {
        int e = grp;
        for (; e + 4 < dc; e += 8) {
            int s0 = csr[node * MAXDEG + e];
            int s1 = csr[node * MAXDEG + e + 4];
            ushort4 u0 = *(const ushort4*)&Y3[(size_t)s0 * 40 + sub * 4];
            ushort4 u1 = *(const ushort4*)&Y3[(size_t)s1 * 40 + sub * 4];
            a0 += bf2f(u0.x) + bf2f(u1.x);
            a1 += bf2f(u0.y) + bf2f(u1.y);
            a2 += bf2f(u0.z) + bf2f(u1.z);
            a3 += bf2f(u0.w) + bf2f(u1.w);
        }
        if (e < dc) {
            int s = csr[node * MAXDEG + e];
            ushort4 u = *(const ushort4*)&Y3[(size_t)s * 40 + sub * 4];
            a0 += bf2f(u.x); a1 += bf2f(u.y); a2 += bf2f(u.z); a3 += bf2f(u.w);
        }
    }
    a0 += __shfl_xor(a0, 16); a0 += __shfl_xor(a0, 32);
    a1 += __shfl_xor(a1, 16); a1 += __shfl_xor(a1, 32);
    a2 += __shfl_xor(a2, 16); a2 += __shfl_xor(a2, 32);
    a3 += __shfl_xor(a3, 16); a3 += __shfl_xor(a3, 32);

    float rs = rsqrtf((float)(d > 1 ? d : 1));
    float x0 = 0.f, x1 = 0.f, x2 = 0.f, x3 = 0.f;
    float mx = -INFINITY;
    if (sub < 10) {
        float4 b = *(const float4*)&b2[sub * 4];
        x0 = a0 * rs + b.x;
        x1 = a1 * rs + b.y;
        x2 = a2 * rs + b.z;
        x3 = a3 * rs + b.w;
        mx = fmaxf(fmaxf(x0, x1), fmaxf(x2, x3));
    }
#pragma unroll
    for (int o = 1; o < 16; o <<= 1) mx = fmaxf(mx, __shfl_xor(mx, o));
    float ex = 0.f;
    if (sub < 10)
        ex = expf(x0 - mx) + expf(x1 - mx) + expf(x2 - mx) + expf(x3 - mx);
#pragma unroll
    for (int o = 1; o < 16; o <<= 1) ex += __shfl_xor(ex, o);
    float ls = logf(ex) + mx;
    if (sub < 10 && grp == 0)
        *(float4*)&out[(size_t)node * 40 + sub * 4] =
            make_float4(x0 - ls, x1 - ls, x2 - ls, x3 - ls);
}

// -------------------- launch --------------------

extern "C" void kernel_launch(void* const* d_in, const int* in_sizes, int n_in,
                              void* d_out, int out_size, void* d_ws, size_t ws_size,
                              hipStream_t stream) {
    const float* features = (const float*)d_in[0];
    const int* src = (const int*)d_in[1];
    const int* dst = (const int*)d_in[2];
    const float* W1 = (const float*)d_in[3];
    const float* Wh = (const float*)d_in[4];
    const float* W2 = (const float*)d_in[5];
    const float* b2 = (const float*)d_in[6];
    float* out = (float*)d_out;

    const int N = in_sizes[0] / 128;
    const int E = in_sizes[1];

    char* p = (char*)d_ws;
    auto carve = [&](size_t bytes) {
        char* q = p;
        p += (bytes + 255) & ~(size_t)255;
        return q;
    };
    unsigned short* bufY1 = (unsigned short*)carve((size_t)N * 128 * 2);
    unsigned short* bufY2 = (unsigned short*)carve((size_t)N * 128 * 2);
    unsigned short* bufY3 = (unsigned short*)carve((size_t)N * 40 * 2);
    int* csr = (int*)carve((size_t)N * MAXDEG * 4);
    int* outdeg = (int*)carve((size_t)N * 4);
    int* indeg = (int*)carve((size_t)N * 4);
    (void)ws_size; (void)n_in; (void)out_size;

    hipMemsetAsync(outdeg, 0, (size_t)N * 4, stream);
    hipMemsetAsync(indeg, 0, (size_t)N * 4, stream);

    int gG = (N + 63) / 64;          // gemm blocks (1563)
    int gE = (E + 2047) / 2048;      // edge blocks, 8 edges/thread (782)
    // K1: CSR build + outdeg hist || gemm1
    edge_gemm1_kernel<<<gG + gE, 256, 0, stream>>>(
        features, W1, bufY1, src, dst, outdeg, indeg, csr, N, E, gG, gE);
    // K2: Y2 = (relu(agg(Y1)) * ln) @ Wh
    agg_gemm2_kernel<<<gG, 512, 0, stream>>>(bufY1, Wh, bufY2, csr, indeg, outdeg, N);
    // K3: Y3 = (relu(agg(Y2) * rn) * ln) @ W2
    agg_gemm3_kernel<<<gG, 512, 0, stream>>>(bufY2, W2, bufY3, csr, indeg, outdeg, N);
    // K4: out = log_softmax(agg(Y3) * rn + b2)
    agg40_lsm_kernel<<<(N + 7) / 8, 512, 0, stream>>>(bufY3, b2, csr, indeg, out, N);
}

// Round 7
// 337.026 us; speedup vs baseline: 1.4495x; 1.2463x over previous
//
#include <hip/hip_runtime.h>
#include <math.h>

#define MAXDEG 64
#define BCAP 8192      // per-bucket capacity (mean ~4096, +64 sigma)
#define EPB 4096       // edges per bucketing block

// -------------------- bf16 helpers --------------------
static __device__ inline unsigned short f2bf(float f) {
    unsigned int u = __float_as_uint(f);
    u += 0x7FFFu + ((u >> 16) & 1u);  // round-nearest-even
    return (unsigned short)(u >> 16);
}
static __device__ inline float bf2f(unsigned short u) {
    return __uint_as_float(((unsigned int)u) << 16);
}
static __device__ inline float4 ld_f4(const float* p) { return *(const float4*)p; }

// accumulate 8 bf16 (packed in uint4) into 8 f32
static __device__ __forceinline__ void acc8(float* a, uint4 u) {
    a[0] += __uint_as_float(u.x << 16);
    a[1] += __uint_as_float(u.x & 0xFFFF0000u);
    a[2] += __uint_as_float(u.y << 16);
    a[3] += __uint_as_float(u.y & 0xFFFF0000u);
    a[4] += __uint_as_float(u.z << 16);
    a[5] += __uint_as_float(u.z & 0xFFFF0000u);
    a[6] += __uint_as_float(u.w << 16);
    a[7] += __uint_as_float(u.w & 0xFFFF0000u);
}

// -------------------- GEMM phases --------------------
static __device__ __forceinline__ void gemm128_phase256(
    const float* sA, const float* __restrict__ W,
    unsigned short* __restrict__ Y, int row0, int t, int N) {
    int tx = t & 31, ty = t >> 5;
    int c0 = tx * 4, r0 = ty * 8;
    float acc[8][4];
#pragma unroll
    for (int i = 0; i < 8; ++i)
#pragma unroll
        for (int c = 0; c < 4; ++c) acc[i][c] = 0.f;

    for (int j = 0; j < 128; j += 4) {
        float w[4][4];
#pragma unroll
        for (int q = 0; q < 4; ++q) {
            float4 t4 = ld_f4(&W[(size_t)(j + q) * 128 + c0]);
            w[q][0] = t4.x; w[q][1] = t4.y; w[q][2] = t4.z; w[q][3] = t4.w;
        }
#pragma unroll
        for (int i = 0; i < 8; ++i) {
            float4 a4 = ld_f4(&sA[(r0 + i) * 128 + j]);
            float a[4] = {a4.x, a4.y, a4.z, a4.w};
#pragma unroll
            for (int q = 0; q < 4; ++q)
#pragma unroll
                for (int c = 0; c < 4; ++c)
                    acc[i][c] = fmaf(a[q], w[q][c], acc[i][c]);
        }
    }
#pragma unroll
    for (int i = 0; i < 8; ++i) {
        int grow = row0 + r0 + i;
        if (grow < N) {
            ushort4 o;
            o.x = f2bf(acc[i][0]); o.y = f2bf(acc[i][1]);
            o.z = f2bf(acc[i][2]); o.w = f2bf(acc[i][3]);
            *(ushort4*)&Y[(size_t)grow * 128 + c0] = o;
        }
    }
}

static __device__ __forceinline__ void gemm128_phase512(
    const float* sA, const float* __restrict__ W,
    unsigned short* __restrict__ Y, int row0, int t, int N) {
    int tx = t & 31, ty = t >> 5;   // ty 0..15
    int c0 = tx * 4, r0 = ty * 4;
    float acc[4][4];
#pragma unroll
    for (int i = 0; i < 4; ++i)
#pragma unroll
        for (int c = 0; c < 4; ++c) acc[i][c] = 0.f;

    for (int j = 0; j < 128; j += 4) {
        float w[4][4];
#pragma unroll
        for (int q = 0; q < 4; ++q) {
            float4 t4 = ld_f4(&W[(size_t)(j + q) * 128 + c0]);
            w[q][0] = t4.x; w[q][1] = t4.y; w[q][2] = t4.z; w[q][3] = t4.w;
        }
#pragma unroll
        for (int i = 0; i < 4; ++i) {
            float4 a4 = ld_f4(&sA[(r0 + i) * 128 + j]);
            float a[4] = {a4.x, a4.y, a4.z, a4.w};
#pragma unroll
            for (int q = 0; q < 4; ++q)
#pragma unroll
                for (int c = 0; c < 4; ++c)
                    acc[i][c] = fmaf(a[q], w[q][c], acc[i][c]);
        }
    }
#pragma unroll
    for (int i = 0; i < 4; ++i) {
        int grow = row0 + r0 + i;
        if (grow < N) {
            ushort4 o;
            o.x = f2bf(acc[i][0]); o.y = f2bf(acc[i][1]);
            o.z = f2bf(acc[i][2]); o.w = f2bf(acc[i][3]);
            *(ushort4*)&Y[(size_t)grow * 128 + c0] = o;
        }
    }
}

static __device__ __forceinline__ void gemm40_phase512(
    const float* sA, const float* __restrict__ W2,
    unsigned short* __restrict__ Y3, int row0, int t, int N) {
    int tx = t & 15, ty = t >> 4;   // ty 0..31
    int c0 = tx * 4, r0 = ty * 2;
    if (tx >= 10) return;
    float acc[2][4];
#pragma unroll
    for (int i = 0; i < 2; ++i)
#pragma unroll
        for (int c = 0; c < 4; ++c) acc[i][c] = 0.f;

    for (int j = 0; j < 128; j += 4) {
        float w[4][4];
#pragma unroll
        for (int q = 0; q < 4; ++q) {
            float4 t4 = ld_f4(&W2[(size_t)(j + q) * 40 + c0]);
            w[q][0] = t4.x; w[q][1] = t4.y; w[q][2] = t4.z; w[q][3] = t4.w;
        }
#pragma unroll
        for (int i = 0; i < 2; ++i) {
            float4 a4 = ld_f4(&sA[(r0 + i) * 128 + j]);
            float a[4] = {a4.x, a4.y, a4.z, a4.w};
#pragma unroll
            for (int q = 0; q < 4; ++q)
#pragma unroll
                for (int c = 0; c < 4; ++c)
                    acc[i][c] = fmaf(a[q], w[q][c], acc[i][c]);
        }
    }
#pragma unroll
    for (int i = 0; i < 2; ++i) {
        int grow = row0 + r0 + i;
        if (grow < N) {
            ushort4 o;
            o.x = f2bf(acc[i][0]); o.y = f2bf(acc[i][1]);
            o.z = f2bf(acc[i][2]); o.w = f2bf(acc[i][3]);
            *(ushort4*)&Y3[(size_t)grow * 40 + c0] = o;
        }
    }
}

// -------------------- gather phase (512 threads) --------------------
// 16 lanes per row (ushort8 = 16B/lane), 4 rows per wave, 4-edge unroll.
template <int MODE>
static __device__ __forceinline__ void gather_phase(
    const unsigned short* __restrict__ Ysrc, float* sA,
    const int* __restrict__ csr, const int* __restrict__ indeg,
    const int* __restrict__ outdeg, int row0, int t, int N) {
    int w = t >> 6;             // wave 0..7
    int l = t & 63;
    int q = l >> 4;             // quarter 0..3 (one row each)
    int lq = l & 15;            // lane within quarter
    int qb = q * 16;            // quarter's base lane in wave

#pragma unroll
    for (int i = 0; i < 2; ++i) {
        int r = i * 32 + w * 4 + q;   // 0..63
        int node = row0 + r;
        bool valid = node < N;
        int d = 0;
        if (valid) d = indeg[node];
        int dc = d > MAXDEG ? MAXDEG : d;

        // stage src indices in up to 4 regs across the 16-lane quarter
        int idx0 = 0, idx1 = 0, idx2 = 0, idx3 = 0;
        if (valid) {
            const int* cp = csr + (size_t)node * MAXDEG;
            idx0 = cp[lq];
            if (dc > 16) idx1 = cp[16 + lq];
            if (dc > 32) idx2 = cp[32 + lq];
            if (dc > 48) idx3 = cp[48 + lq];
        }

        float a[8];
#pragma unroll
        for (int x = 0; x < 8; ++x) a[x] = 0.f;

#pragma unroll
        for (int k = 0; k < 4; ++k) {
            int kbase = k * 16;
            if (kbase >= dc) break;
            int v = (k == 0) ? idx0 : (k == 1) ? idx1 : (k == 2) ? idx2 : idx3;
            int lim = dc - kbase;
            if (lim > 16) lim = 16;
            int e = 0;
            for (; e + 4 <= lim; e += 4) {
                int s0 = __shfl(v, qb + e);
                int s1 = __shfl(v, qb + e + 1);
                int s2 = __shfl(v, qb + e + 2);
                int s3 = __shfl(v, qb + e + 3);
                uint4 u0 = *(const uint4*)&Ysrc[(size_t)s0 * 128 + lq * 8];
                uint4 u1 = *(const uint4*)&Ysrc[(size_t)s1 * 128 + lq * 8];
                uint4 u2 = *(const uint4*)&Ysrc[(size_t)s2 * 128 + lq * 8];
                uint4 u3 = *(const uint4*)&Ysrc[(size_t)s3 * 128 + lq * 8];
                acc8(a, u0); acc8(a, u1); acc8(a, u2); acc8(a, u3);
            }
            for (; e < lim; ++e) {
                int s0 = __shfl(v, qb + e);
                uint4 u0 = *(const uint4*)&Ysrc[(size_t)s0 * 128 + lq * 8];
                acc8(a, u0);
            }
        }

        if (valid) {
            int od = outdeg[node];
            float ln = rsqrtf((float)(od > 1 ? od : 1));
            if (MODE == 0) {
#pragma unroll
                for (int x = 0; x < 8; ++x) a[x] = fmaxf(a[x], 0.f) * ln;
            } else {
                float rn = rsqrtf((float)(d > 1 ? d : 1));
#pragma unroll
                for (int x = 0; x < 8; ++x) a[x] = fmaxf(a[x] * rn, 0.f) * ln;
            }
        }
        *(float4*)&sA[r * 128 + lq * 8] = make_float4(a[0], a[1], a[2], a[3]);
        *(float4*)&sA[r * 128 + lq * 8 + 4] = make_float4(a[4], a[5], a[6], a[7]);
    }
}

// ==================== K1: edge bucketing (B1) || GEMM1 ====================
// B1 block: 4096 edges -> LDS bucket histograms (dst>>8, src>>8), one global
// atomicAdd per touched bucket for the base, then scatter packed entries.
static __global__ __launch_bounds__(256) void bucket_gemm1_kernel(
    const float* __restrict__ A, const float* __restrict__ W,
    unsigned short* __restrict__ Y,
    const int* __restrict__ src, const int* __restrict__ dst,
    int* __restrict__ cntD, int* __restrict__ cntS,
    unsigned int* __restrict__ bktD, unsigned char* __restrict__ bktS,
    int N, int E, int nb, int gG, int gB) {
    __shared__ float sA[64 * 128];  // 32 KB; B1 role reuses as int scratch
    int bid = blockIdx.x;
    int t = threadIdx.x;

    // interleave ~1 B1 block per 4 gemm blocks
    int nI = 5 * gB;
    int role, idx;
    if (bid < nI) {
        if (bid % 5 == 0) { role = 1; idx = bid / 5; }
        else { role = 0; idx = bid - bid / 5 - 1; }
    } else { role = 0; idx = bid - gB; }
    if (role == 1 && idx >= gB) return;
    if (role == 0 && idx >= gG) return;

    if (role == 1) {
        int* sh = (int*)sA;
        int* hD = sh;            // [512] dst-bucket histogram
        int* hS = sh + 512;      // [512] src-bucket histogram
        int* bD = sh + 1024;     // [512] dst base offsets
        int* bS = sh + 1536;     // [512] src base offsets
        int* cD = sh + 2048;     // [512] dst cursors
        int* cS = sh + 2560;     // [512] src cursors
        for (int i = t; i < 512; i += 256) {
            hD[i] = 0; hS[i] = 0; cD[i] = 0; cS[i] = 0;
        }
        __syncthreads();

        int base = idx * EPB + t * 16;
        int s_r[16], d_r[16];
        int nv = 0;
        if (base + 16 <= E) {
            nv = 16;
#pragma unroll
            for (int k = 0; k < 4; ++k) {
                int4 sv = *(const int4*)&src[base + k * 4];
                int4 dv = *(const int4*)&dst[base + k * 4];
                s_r[k * 4 + 0] = sv.x; s_r[k * 4 + 1] = sv.y;
                s_r[k * 4 + 2] = sv.z; s_r[k * 4 + 3] = sv.w;
                d_r[k * 4 + 0] = dv.x; d_r[k * 4 + 1] = dv.y;
                d_r[k * 4 + 2] = dv.z; d_r[k * 4 + 3] = dv.w;
            }
        } else {
            nv = E - base; if (nv < 0) nv = 0; if (nv > 16) nv = 16;
#pragma unroll
            for (int k = 0; k < 16; ++k) {
                if (k < nv) { s_r[k] = src[base + k]; d_r[k] = dst[base + k]; }
                else { s_r[k] = 0; d_r[k] = 0; }
            }
        }

#pragma unroll
        for (int k = 0; k < 16; ++k) {
            if (k < nv) {
                atomicAdd(&hD[d_r[k] >> 8], 1);
                atomicAdd(&hS[s_r[k] >> 8], 1);
            }
        }
        __syncthreads();

        for (int b = t; b < nb; b += 256) {
            int h = hD[b];
            bD[b] = h ? atomicAdd(&cntD[b], h) : 0;
            int h2 = hS[b];
            bS[b] = h2 ? atomicAdd(&cntS[b], h2) : 0;
        }
        __syncthreads();

#pragma unroll
        for (int k = 0; k < 16; ++k) {
            if (k < nv) {
                int d = d_r[k], s = s_r[k];
                int bb = d >> 8;
                int p = atomicAdd(&cD[bb], 1) + bD[bb];
                if (p < BCAP)
                    bktD[(size_t)bb * BCAP + p] =
                        ((unsigned int)(d & 255) << 17) | (unsigned int)s;
                int sb = s >> 8;
                int p2 = atomicAdd(&cS[sb], 1) + bS[sb];
                if (p2 < BCAP)
                    bktS[(size_t)sb * BCAP + p2] = (unsigned char)(s & 255);
            }
        }
        return;
    }

    // ---- gemm1 ----
    int row0 = idx * 64;
#pragma unroll
    for (int i = 0; i < 8; ++i) {
        int fi = i * 256 + t;
        int r = fi >> 5;
        int c4 = (fi & 31) * 4;
        int grow = row0 + r;
        float4 v = make_float4(0.f, 0.f, 0.f, 0.f);
        if (grow < N) v = ld_f4(&A[(size_t)grow * 128 + c4]);
        *(float4*)&sA[r * 128 + c4] = v;
    }
    __syncthreads();
    gemm128_phase256(sA, W, Y, row0, t, N);
}

// ==================== K1b: per-bucket CSR build (B2) ====================
// bid < nb : dst bucket -> csr slices + indeg (LDS cursors, no global atomics)
// bid >= nb: src bucket -> outdeg (LDS histogram)
static __global__ __launch_bounds__(256) void csr_build_kernel(
    const int* __restrict__ cntD, const int* __restrict__ cntS,
    const unsigned int* __restrict__ bktD, const unsigned char* __restrict__ bktS,
    int* __restrict__ csr, int* __restrict__ indeg, int* __restrict__ outdeg,
    int N, int nb) {
    __shared__ int cur[256];
    int bid = blockIdx.x;
    int t = threadIdx.x;
    cur[t] = 0;
    __syncthreads();

    if (bid < nb) {
        int b = bid;
        int cnt = cntD[b]; if (cnt > BCAP) cnt = BCAP;
        const unsigned int* bp = bktD + (size_t)b * BCAP;
        for (int i = t; i < cnt; i += 256) {
            unsigned int v = bp[i];
            int d8 = v >> 17;
            int s = (int)(v & 0x1FFFFu);
            int p = atomicAdd(&cur[d8], 1);
            if (p < MAXDEG) csr[((size_t)(b * 256 + d8)) * MAXDEG + p] = s;
        }
        __syncthreads();
        int node = b * 256 + t;
        if (node < N) indeg[node] = cur[t];
    } else {
        int b = bid - nb;
        int cnt = cntS[b]; if (cnt > BCAP) cnt = BCAP;
        const unsigned char* bp = bktS + (size_t)b * BCAP;
        for (int i = t; i < cnt; i += 256) atomicAdd(&cur[bp[i]], 1);
        __syncthreads();
        int node = b * 256 + t;
        if (node < N) outdeg[node] = cur[t];
    }
}

// ==================== K2: agg(Y1)+relu+ln @ Wh ====================
static __global__ __launch_bounds__(512) void agg_gemm2_kernel(
    const unsigned short* __restrict__ Y1, const float* __restrict__ Wh,
    unsigned short* __restrict__ Y2,
    const int* __restrict__ csr, const int* __restrict__ indeg,
    const int* __restrict__ outdeg, int N) {
    __shared__ float sA[64 * 128];
    int t = threadIdx.x;
    int row0 = blockIdx.x * 64;
    gather_phase<0>(Y1, sA, csr, indeg, outdeg, row0, t, N);
    __syncthreads();
    gemm128_phase512(sA, Wh, Y2, row0, t, N);
}

// ==================== K3: agg(Y2)*rn,relu,*ln @ W2 ====================
static __global__ __launch_bounds__(512) void agg_gemm3_kernel(
    const unsigned short* __restrict__ Y2, const float* __restrict__ W2,
    unsigned short* __restrict__ Y3,
    const int* __restrict__ csr, const int* __restrict__ indeg,
    const int* __restrict__ outdeg, int N) {
    __shared__ float sA[64 * 128];
    int t = threadIdx.x;
    int row0 = blockIdx.x * 64;
    gather_phase<1>(Y2, sA, csr, indeg, outdeg, row0, t, N);
    __syncthreads();
    gemm40_phase512(sA, W2, Y3, row0, t, N);
}

// ========== K4: agg(Y3)*rn + b2 + log_softmax ==========
static __global__ __launch_bounds__(512) void agg40_lsm_kernel(
    const unsigned short* __restrict__ Y3, const float* __restrict__ b2,
    const int* __restrict__ csr, const int* __restrict__ indeg,
    float* __restrict__ out, int N) {
    int t = threadIdx.x;
    int node = blockIdx.x * 8 + (t >> 6);
    if (node >= N) return;
    int lane = t & 63;
    int grp = lane >> 4;   // 0..3  : edge group
    int sub = lane & 15;   // 0..15 : dim group (10 active)
    int d = indeg[node];
    int dc = d > MAXDEG ? MAXDEG : d;

    float a0 = 0.f, a1 = 0.f, a2 = 0.f, a3 = 0.f;
    if (sub < 10) {
        int e = grp;
        for (; e + 4 < dc; e += 8) {
            int s0 = csr[node * MAXDEG + e];
            int s1 = csr[node * MAXDEG + e + 4];
            ushort4 u0 = *(const ushort4*)&Y3[(size_t)s0 * 40 + sub * 4];
            ushort4 u1 = *(const ushort4*)&Y3[(size_t)s1 * 40 + sub * 4];
            a0 += bf2f(u0.x) + bf2f(u1.x);
            a1 += bf2f(u0.y) + bf2f(u1.y);
            a2 += bf2f(u0.z) + bf2f(u1.z);
            a3 += bf2f(u0.w) + bf2f(u1.w);
        }
        if (e < dc) {
            int s = csr[node * MAXDEG + e];
            ushort4 u = *(const ushort4*)&Y3[(size_t)s * 40 + sub * 4];
            a0 += bf2f(u.x); a1 += bf2f(u.y); a2 += bf2f(u.z); a3 += bf2f(u.w);
        }
    }
    a0 += __shfl_xor(a0, 16); a0 += __shfl_xor(a0, 32);
    a1 += __shfl_xor(a1, 16); a1 += __shfl_xor(a1, 32);
    a2 += __shfl_xor(a2, 16); a2 += __shfl_xor(a2, 32);
    a3 += __shfl_xor(a3, 16); a3 += __shfl_xor(a3, 32);

    float rs = rsqrtf((float)(d > 1 ? d : 1));
    float x0 = 0.f, x1 = 0.f, x2 = 0.f, x3 = 0.f;
    float mx = -INFINITY;
    if (sub < 10) {
        float4 b = *(const float4*)&b2[sub * 4];
        x0 = a0 * rs + b.x;
        x1 = a1 * rs + b.y;
        x2 = a2 * rs + b.z;
        x3 = a3 * rs + b.w;
        mx = fmaxf(fmaxf(x0, x1), fmaxf(x2, x3));
    }
#pragma unroll
    for (int o = 1; o < 16; o <<= 1) mx = fmaxf(mx, __shfl_xor(mx, o));
    float ex = 0.f;
    if (sub < 10)
        ex = expf(x0 - mx) + expf(x1 - mx) + expf(x2 - mx) + expf(x3 - mx);
#pragma unroll
    for (int o = 1; o < 16; o <<= 1) ex += __shfl_xor(ex, o);
    float ls = logf(ex) + mx;
    if (sub < 10 && grp == 0)
        *(float4*)&out[(size_t)node * 40 + sub * 4] =
            make_float4(x0 - ls, x1 - ls, x2 - ls, x3 - ls);
}

// -------------------- launch --------------------

extern "C" void kernel_launch(void* const* d_in, const int* in_sizes, int n_in,
                              void* d_out, int out_size, void* d_ws, size_t ws_size,
                              hipStream_t stream) {
    const float* features = (const float*)d_in[0];
    const int* src = (const int*)d_in[1];
    const int* dst = (const int*)d_in[2];
    const float* W1 = (const float*)d_in[3];
    const float* Wh = (const float*)d_in[4];
    const float* W2 = (const float*)d_in[5];
    const float* b2 = (const float*)d_in[6];
    float* out = (float*)d_out;

    const int N = in_sizes[0] / 128;
    const int E = in_sizes[1];
    const int nb = (N + 255) / 256;   // node buckets of 256

    char* p = (char*)d_ws;
    auto carve = [&](size_t bytes) {
        char* q = p;
        p += (bytes + 255) & ~(size_t)255;
        return q;
    };
    unsigned short* bufY1 = (unsigned short*)carve((size_t)N * 128 * 2);
    unsigned short* bufY2 = (unsigned short*)carve((size_t)N * 128 * 2);
    unsigned short* bufY3 = (unsigned short*)carve((size_t)N * 40 * 2);
    int* csr = (int*)carve((size_t)N * MAXDEG * 4);
    unsigned int* bktD = (unsigned int*)carve((size_t)nb * BCAP * 4);
    unsigned char* bktS = (unsigned char*)carve((size_t)nb * BCAP);
    int* cntD = (int*)carve((size_t)nb * 4);
    int* cntS = (int*)carve((size_t)nb * 4);
    int* indeg = (int*)carve((size_t)N * 4);
    int* outdeg = (int*)carve((size_t)N * 4);
    (void)ws_size; (void)n_in; (void)out_size;

    hipMemsetAsync(cntD, 0, (size_t)nb * 4, stream);
    hipMemsetAsync(cntS, 0, (size_t)nb * 4, stream);

    int gG = (N + 63) / 64;          // gemm blocks
    int gB = (E + EPB - 1) / EPB;    // bucketing blocks (16 edges/thread)
    // K1: edge bucketing || gemm1
    bucket_gemm1_kernel<<<gG + gB, 256, 0, stream>>>(
        features, W1, bufY1, src, dst, cntD, cntS, bktD, bktS, N, E, nb, gG, gB);
    // K1b: per-bucket CSR/indeg (dst) + outdeg (src), LDS cursors only
    csr_build_kernel<<<2 * nb, 256, 0, stream>>>(
        cntD, cntS, bktD, bktS, csr, indeg, outdeg, N, nb);
    // K2: Y2 = (relu(agg(Y1)) * ln) @ Wh
    agg_gemm2_kernel<<<gG, 512, 0, stream>>>(bufY1, Wh, bufY2, csr, indeg, outdeg, N);
    // K3: Y3 = (relu(agg(Y2) * rn) * ln) @ W2
    agg_gemm3_kernel<<<gG, 512, 0, stream>>>(bufY2, W2, bufY3, csr, indeg, outdeg, N);
    // K4: out = log_softmax(agg(Y3) * rn + b2)
    agg40_lsm_kernel<<<(N + 7) / 8, 512, 0, stream>>>(bufY3, b2, csr, indeg, out, N);
}